// Round 12
// baseline (208.615 us; speedup 1.0000x reference)
//
#include <hip/hip_runtime.h>
#include <math.h>

#define NOUT 64
#define NIN  64
#define HH   32
#define WW   32
#define XCPL 137                         // per-channel LDS plane stride (4 rows * 34 cols + 1)
#define XWORDS (4 * 34 * NIN)            // 8704 staged x words
#define WPK_WORDS (NOUT * 9 * 3 * NIN * 4)  // 442368 packed weight words (1.77 MB)
#define WN_WORDS  (NOUT * NIN * 9 * 6)   // 221184
#define WD_WORDS  (NOUT * NIN * 9 * 4)   // 147456
#define NBLK 1024                        // 64 f * 16 two-row bands

typedef float f4 __attribute__((ext_vector_type(4)));

// ---------- prep: pack weights to [f][ab][q][c][4]; thread = src word (coalesced reads) ----------
// q0={a0..a3} q1={a4,a5,b0,b1} q2={b2,b3,pad,pad} (pads never consumed)
__global__ __launch_bounds__(256) void wpack_kernel(const float* __restrict__ wn,
                                                    const float* __restrict__ wd,
                                                    float* __restrict__ wpk) {
    int idx = blockIdx.x * 256 + threadIdx.x;    // 368640 = 1440 * 256 exact
    if (idx < WN_WORDS) {
        int n  = idx % 6;
        int t  = idx / 6;
        int ab = t % 9;
        int t2 = t / 9;
        int c  = t2 & 63;
        int f  = t2 >> 6;
        int q  = (n < 4) ? 0 : 1;
        int e  = (n < 4) ? n : n - 4;
        wpk[((f * 9 + ab) * 3 + q) * 256 + c * 4 + e] = wn[idx];
    } else {
        int id2 = idx - WN_WORDS;
        int n  = id2 & 3;
        int t  = id2 >> 2;
        int ab = t % 9;
        int t2 = t / 9;
        int c  = t2 & 63;
        int f  = t2 >> 6;
        int q  = (n < 2) ? 1 : 2;
        int e  = (n < 2) ? 2 + n : n - 2;
        wpk[((f * 9 + ab) * 3 + q) * 256 + c * 4 + e] = wd[id2];
    }
}

// ---------- main: block = (f, 2-row band); wave = 8-pixel strip; lane = channel c.
// x in LDS (lgkmcnt), weights via coalesced VMEM float4 (vmcnt), P=8 amortization.
__global__ __launch_bounds__(512, 8) void kan_main(const float* __restrict__ x,
                                                   const float* __restrict__ wpk,
                                                   float* __restrict__ out) {
    __shared__ float xt[NIN * XCPL];     // 35072 B

    // bijective XCD-chunked swizzle: 1024 blocks, 128 per XCD -> 8 f's per XCD
    int bid  = blockIdx.x;
    int wgid = (bid & 7) * (NBLK / 8) + (bid >> 3);
    int f    = wgid >> 4;
    int band = wgid & 15;
    int i0   = band * 2;

    int tid = threadIdx.x;

    // ---- stage x rows i0-1..i0+2, cols -1..32, 64 c; reads c-coalesced;
    // ---- LDS word = c*137 + t -> bank (9c+t)%32 -> 2-way (free) ----
#pragma unroll
    for (int k = 0; k < 17; ++k) {
        int idx = k * 512 + tid;         // 8704 = 17*512 exact
        int c   = idx & 63;
        int t   = idx >> 6;              // 0..135
        int row = t / 34;
        int col = t % 34;
        int gi  = i0 - 1 + row;
        int gj  = col - 1;
        float v = 0.0f;
        if (gi >= 0 && gi < HH && gj >= 0 && gj < WW)
            v = x[(gi * WW + gj) * NIN + c];
        xt[c * XCPL + t] = v;
    }
    __syncthreads();

    int lane = tid & 63;                 // = input channel c
    int wid  = tid >> 6;                 // 0..7
    int r    = wid >> 2;                 // pixel row within band: 0..1
    int j0   = (wid & 3) * 8;            // pixel-strip start col

    float acc[8];
#pragma unroll
    for (int p = 0; p < 8; ++p) acc[p] = 0.0f;

    const f4* wb = (const f4*)wpk + (size_t)f * 1728 + lane;   // [ab]*192 + q*64
    const float* xb0 = &xt[lane * XCPL + r * 34 + j0];

#pragma unroll
    for (int a = 0; a < 3; ++a) {
        float xr[10];
#pragma unroll
        for (int t = 0; t < 10; ++t)
            xr[t] = xb0[a * 34 + t];     // ds_read_b32, imm offsets, 2-way max
#pragma unroll
        for (int b = 0; b < 3; ++b) {
            const int ab = a * 3 + b;
            f4 w0 = wb[ab * 192];        // a0 a1 a2 a3  (1 KiB/instr coalesced, L1)
            f4 w1 = wb[ab * 192 + 64];   // a4 a5 b0 b1
            f4 w2 = wb[ab * 192 + 128];  // b2 b3 --- ---
#pragma unroll
            for (int p = 0; p < 8; ++p) {
                float xv = xr[p + b];
                float pn = fmaf(w1.y, xv, w1.x);
                pn = fmaf(pn, xv, w0.w);
                pn = fmaf(pn, xv, w0.z);
                pn = fmaf(pn, xv, w0.y);
                pn = fmaf(pn, xv, w0.x);
                float qn = fmaf(w2.y, xv, w2.x);
                qn = fmaf(qn, xv, w1.w);
                qn = fmaf(qn, xv, w1.z);
                float den = 1.0f + fabsf(xv * qn);
                acc[p] = fmaf(pn, __builtin_amdgcn_rcpf(den), acc[p]);
            }
        }
    }

    // ---- reduce over lanes (channels); lane p writes pixel p ----
#pragma unroll
    for (int p = 0; p < 8; ++p) {
        float s = acc[p];
        s += __shfl_xor(s, 32, 64);
        s += __shfl_xor(s, 16, 64);
        s += __shfl_xor(s, 8, 64);
        s += __shfl_xor(s, 4, 64);
        s += __shfl_xor(s, 2, 64);
        s += __shfl_xor(s, 1, 64);
        if (lane == p) out[f * (HH * WW) + (i0 + r) * WW + j0 + p] = s;
    }
}

// ---------- fallback (tiny ws): R6 structure, proven at 24 us ----------
__global__ __launch_bounds__(512, 8) void kan_fallback(const float* __restrict__ x,
                                                       const float* __restrict__ wn,
                                                       const float* __restrict__ wd,
                                                       float* __restrict__ out) {
    __shared__ float xt[NIN * 137];
    __shared__ float red[512];
    int bid  = blockIdx.x;
    int wgid = (bid & 7) * 128 + (bid >> 3);
    int f    = wgid >> 4;
    int band = wgid & 15;
    int i0   = band * 2;
    int tid = threadIdx.x;
#pragma unroll
    for (int k = 0; k < 17; ++k) {
        int idx = k * 512 + tid;
        int c   = idx & 63;
        int t   = idx >> 6;
        int row = t / 34;
        int col = t % 34;
        int gi  = i0 - 1 + row;
        int gj  = col - 1;
        float v = 0.0f;
        if (gi >= 0 && gi < HH && gj >= 0 && gj < WW)
            v = x[(gi * WW + gj) * NIN + c];
        xt[c * 137 + t] = v;
    }
    __syncthreads();
    int lane = tid & 63;
    int wv   = __builtin_amdgcn_readfirstlane(tid >> 6);
    int r    = lane >> 5;
    int j    = lane & 31;
    float acc = 0.0f;
    const float* wnf = wn + (size_t)(f * NIN + wv * 8) * 54;
    const float* wdf = wd + (size_t)(f * NIN + wv * 8) * 36;
    for (int cc = 0; cc < 8; ++cc) {
        const float* wnc = wnf + cc * 54;
        const float* wdc = wdf + cc * 36;
        const float* xc  = &xt[(wv * 8 + cc) * 137 + r * 34 + j];
#pragma unroll
        for (int a = 0; a < 3; ++a)
#pragma unroll
            for (int b = 0; b < 3; ++b) {
                const int ab = a * 3 + b;
                float xv = xc[a * 34 + b];
                float pn = fmaf(wnc[ab * 6 + 5], xv, wnc[ab * 6 + 4]);
                pn = fmaf(pn, xv, wnc[ab * 6 + 3]);
                pn = fmaf(pn, xv, wnc[ab * 6 + 2]);
                pn = fmaf(pn, xv, wnc[ab * 6 + 1]);
                pn = fmaf(pn, xv, wnc[ab * 6 + 0]);
                float qn = fmaf(wdc[ab * 4 + 3], xv, wdc[ab * 4 + 2]);
                qn = fmaf(qn, xv, wdc[ab * 4 + 1]);
                qn = fmaf(qn, xv, wdc[ab * 4 + 0]);
                float den = 1.0f + fabsf(xv * qn);
                acc = fmaf(pn, __builtin_amdgcn_rcpf(den), acc);
            }
    }
    red[tid] = acc;
    __syncthreads();
    if (tid < 64) {
        float s = red[tid]       + red[tid + 64]  + red[tid + 128] + red[tid + 192]
                + red[tid + 256] + red[tid + 320] + red[tid + 384] + red[tid + 448];
        out[f * (HH * WW) + (i0 + (tid >> 5)) * WW + (tid & 31)] = s;
    }
}

extern "C" void kernel_launch(void* const* d_in, const int* in_sizes, int n_in,
                              void* d_out, int out_size, void* d_ws, size_t ws_size,
                              hipStream_t stream) {
    const float* x  = (const float*)d_in[0];
    const float* wn = (const float*)d_in[1];
    const float* wd = (const float*)d_in[2];
    float* out = (float*)d_out;
    (void)in_sizes; (void)n_in; (void)out_size;

    if (ws_size >= (size_t)WPK_WORDS * sizeof(float)) {
        float* wpk = (float*)d_ws;
        wpack_kernel<<<(WN_WORDS + WD_WORDS) / 256, 256, 0, stream>>>(wn, wd, wpk);
        kan_main<<<NBLK, 512, 0, stream>>>(x, wpk, out);
    } else {
        kan_fallback<<<1024, 512, 0, stream>>>(x, wn, wd, out);
    }
}

// Round 13
// 40.275 us; speedup vs baseline: 5.1798x; 5.1798x over previous
//
#include <hip/hip_runtime.h>
#include <math.h>

#define NOUT 64
#define NIN  64
#define HH   32
#define WW   32
#define XCPL 137                         // per-channel LDS plane stride (4 rows * 34 cols + 1)
#define XWORDS (4 * 34 * NIN)            // 8704 staged x words
#define WPK_WORDS (NOUT * 9 * 3 * NIN * 4)  // 442368 packed weight words (1.77 MB)
#define WN_WORDS  (NOUT * NIN * 9 * 6)   // 221184
#define WD_WORDS  (NOUT * NIN * 9 * 4)   // 147456
#define NBLK 1024                        // 64 f * 16 two-row bands

typedef float f4 __attribute__((ext_vector_type(4)));

// ---------- prep: pack weights to [f][ab][q][c][4]; thread = src word (coalesced reads) ----------
// q0={a0..a3} q1={a4,a5,b0,b1} q2={b2,b3,pad,pad} (pads never consumed)
__global__ __launch_bounds__(256) void wpack_kernel(const float* __restrict__ wn,
                                                    const float* __restrict__ wd,
                                                    float* __restrict__ wpk) {
    int idx = blockIdx.x * 256 + threadIdx.x;    // 368640 = 1440 * 256 exact
    if (idx < WN_WORDS) {
        int n  = idx % 6;
        int t  = idx / 6;
        int ab = t % 9;
        int t2 = t / 9;
        int c  = t2 & 63;
        int f  = t2 >> 6;
        int q  = (n < 4) ? 0 : 1;
        int e  = (n < 4) ? n : n - 4;
        wpk[((f * 9 + ab) * 3 + q) * 256 + c * 4 + e] = wn[idx];
    } else {
        int id2 = idx - WN_WORDS;
        int n  = id2 & 3;
        int t  = id2 >> 2;
        int ab = t % 9;
        int t2 = t / 9;
        int c  = t2 & 63;
        int f  = t2 >> 6;
        int q  = (n < 2) ? 1 : 2;
        int e  = (n < 2) ? 2 + n : n - 2;
        wpk[((f * 9 + ab) * 3 + q) * 256 + c * 4 + e] = wd[id2];
    }
}

// ---------- main: block = (f, 2-row band); wave = 8-pixel strip; lane = channel c.
// x in LDS (lgkmcnt), weights via coalesced VMEM float4 (vmcnt), P=8 amortization.
// __launch_bounds__ 2nd arg is min BLOCKS/CU (CUDA semantics, confirmed R11/R12):
// (512,2) -> 16 waves/CU -> 128-VGPR cap -> no spill for ~60-80 VGPR working set.
__global__ __launch_bounds__(512, 2) void kan_main(const float* __restrict__ x,
                                                   const float* __restrict__ wpk,
                                                   float* __restrict__ out) {
    __shared__ float xt[NIN * XCPL];     // 35072 B

    // bijective XCD-chunked swizzle: 1024 blocks, 128 per XCD -> 8 f's per XCD
    int bid  = blockIdx.x;
    int wgid = (bid & 7) * (NBLK / 8) + (bid >> 3);
    int f    = wgid >> 4;
    int band = wgid & 15;
    int i0   = band * 2;

    int tid = threadIdx.x;

    // ---- stage x rows i0-1..i0+2, cols -1..32, 64 c; reads c-coalesced;
    // ---- LDS word = c*137 + t -> bank (9c+t)%32 -> 2-way (free) ----
#pragma unroll
    for (int k = 0; k < 17; ++k) {
        int idx = k * 512 + tid;         // 8704 = 17*512 exact
        int c   = idx & 63;
        int t   = idx >> 6;              // 0..135
        int row = t / 34;
        int col = t % 34;
        int gi  = i0 - 1 + row;
        int gj  = col - 1;
        float v = 0.0f;
        if (gi >= 0 && gi < HH && gj >= 0 && gj < WW)
            v = x[(gi * WW + gj) * NIN + c];
        xt[c * XCPL + t] = v;
    }
    __syncthreads();

    int lane = tid & 63;                 // = input channel c
    int wid  = tid >> 6;                 // 0..7
    int r    = wid >> 2;                 // pixel row within band: 0..1
    int j0   = (wid & 3) * 8;            // pixel-strip start col

    float acc[8];
#pragma unroll
    for (int p = 0; p < 8; ++p) acc[p] = 0.0f;

    const f4* wb = (const f4*)wpk + (size_t)f * 1728 + lane;   // [ab]*192 + q*64
    const float* xb0 = &xt[lane * XCPL + r * 34 + j0];

#pragma unroll
    for (int a = 0; a < 3; ++a) {
        float xr[10];
#pragma unroll
        for (int t = 0; t < 10; ++t)
            xr[t] = xb0[a * 34 + t];     // ds_read_b32, imm offsets, 2-way max
#pragma unroll
        for (int b = 0; b < 3; ++b) {
            const int ab = a * 3 + b;
            f4 w0 = wb[ab * 192];        // a0 a1 a2 a3  (1 KiB/instr coalesced)
            f4 w1 = wb[ab * 192 + 64];   // a4 a5 b0 b1
            f4 w2 = wb[ab * 192 + 128];  // b2 b3 --- ---
#pragma unroll
            for (int p = 0; p < 8; ++p) {
                float xv = xr[p + b];
                float pn = fmaf(w1.y, xv, w1.x);
                pn = fmaf(pn, xv, w0.w);
                pn = fmaf(pn, xv, w0.z);
                pn = fmaf(pn, xv, w0.y);
                pn = fmaf(pn, xv, w0.x);
                float qn = fmaf(w2.y, xv, w2.x);
                qn = fmaf(qn, xv, w1.w);
                qn = fmaf(qn, xv, w1.z);
                float den = 1.0f + fabsf(xv * qn);
                acc[p] = fmaf(pn, __builtin_amdgcn_rcpf(den), acc[p]);
            }
        }
    }

    // ---- reduce over lanes (channels); lane p writes pixel p ----
#pragma unroll
    for (int p = 0; p < 8; ++p) {
        float s = acc[p];
        s += __shfl_xor(s, 32, 64);
        s += __shfl_xor(s, 16, 64);
        s += __shfl_xor(s, 8, 64);
        s += __shfl_xor(s, 4, 64);
        s += __shfl_xor(s, 2, 64);
        s += __shfl_xor(s, 1, 64);
        if (lane == p) out[f * (HH * WW) + (i0 + r) * WW + j0 + p] = s;
    }
}

// ---------- fallback (tiny ws): R6 structure, proven at ~24 us ----------
__global__ __launch_bounds__(512, 4) void kan_fallback(const float* __restrict__ x,
                                                       const float* __restrict__ wn,
                                                       const float* __restrict__ wd,
                                                       float* __restrict__ out) {
    __shared__ float xt[NIN * 137];
    __shared__ float red[512];
    int bid  = blockIdx.x;
    int wgid = (bid & 7) * 128 + (bid >> 3);
    int f    = wgid >> 4;
    int band = wgid & 15;
    int i0   = band * 2;
    int tid = threadIdx.x;
#pragma unroll
    for (int k = 0; k < 17; ++k) {
        int idx = k * 512 + tid;
        int c   = idx & 63;
        int t   = idx >> 6;
        int row = t / 34;
        int col = t % 34;
        int gi  = i0 - 1 + row;
        int gj  = col - 1;
        float v = 0.0f;
        if (gi >= 0 && gi < HH && gj >= 0 && gj < WW)
            v = x[(gi * WW + gj) * NIN + c];
        xt[c * 137 + t] = v;
    }
    __syncthreads();
    int lane = tid & 63;
    int wv   = __builtin_amdgcn_readfirstlane(tid >> 6);
    int r    = lane >> 5;
    int j    = lane & 31;
    float acc = 0.0f;
    const float* wnf = wn + (size_t)(f * NIN + wv * 8) * 54;
    const float* wdf = wd + (size_t)(f * NIN + wv * 8) * 36;
    for (int cc = 0; cc < 8; ++cc) {
        const float* wnc = wnf + cc * 54;
        const float* wdc = wdf + cc * 36;
        const float* xc  = &xt[(wv * 8 + cc) * 137 + r * 34 + j];
#pragma unroll
        for (int a = 0; a < 3; ++a)
#pragma unroll
            for (int b = 0; b < 3; ++b) {
                const int ab = a * 3 + b;
                float xv = xc[a * 34 + b];
                float pn = fmaf(wnc[ab * 6 + 5], xv, wnc[ab * 6 + 4]);
                pn = fmaf(pn, xv, wnc[ab * 6 + 3]);
                pn = fmaf(pn, xv, wnc[ab * 6 + 2]);
                pn = fmaf(pn, xv, wnc[ab * 6 + 1]);
                pn = fmaf(pn, xv, wnc[ab * 6 + 0]);
                float qn = fmaf(wdc[ab * 4 + 3], xv, wdc[ab * 4 + 2]);
                qn = fmaf(qn, xv, wdc[ab * 4 + 1]);
                qn = fmaf(qn, xv, wdc[ab * 4 + 0]);
                float den = 1.0f + fabsf(xv * qn);
                acc = fmaf(pn, __builtin_amdgcn_rcpf(den), acc);
            }
    }
    red[tid] = acc;
    __syncthreads();
    if (tid < 64) {
        float s = red[tid]       + red[tid + 64]  + red[tid + 128] + red[tid + 192]
                + red[tid + 256] + red[tid + 320] + red[tid + 384] + red[tid + 448];
        out[f * (HH * WW) + (i0 + (tid >> 5)) * WW + (tid & 31)] = s;
    }
}

extern "C" void kernel_launch(void* const* d_in, const int* in_sizes, int n_in,
                              void* d_out, int out_size, void* d_ws, size_t ws_size,
                              hipStream_t stream) {
    const float* x  = (const float*)d_in[0];
    const float* wn = (const float*)d_in[1];
    const float* wd = (const float*)d_in[2];
    float* out = (float*)d_out;
    (void)in_sizes; (void)n_in; (void)out_size;

    if (ws_size >= (size_t)WPK_WORDS * sizeof(float)) {
        float* wpk = (float*)d_ws;
        wpack_kernel<<<(WN_WORDS + WD_WORDS) / 256, 256, 0, stream>>>(wn, wd, wpk);
        kan_main<<<NBLK, 512, 0, stream>>>(x, wpk, out);
    } else {
        kan_fallback<<<1024, 512, 0, stream>>>(x, wn, wd, out);
    }
}

// Round 14
// 24.860 us; speedup vs baseline: 8.3916x; 1.6201x over previous
//
#include <hip/hip_runtime.h>
#include <math.h>

#define NOUT 64
#define NIN  64
#define HH   32
#define WW   32
#define XSTR 137                        // LDS row stride (odd -> conflict-free scatter)

// ---------- single kernel: block = (f, 2-row band); wave = 8-channel group;
// ---------- lanes = 64 pixels (2 rows x 32 cols); weights via scalar pipe ----------
// __launch_bounds__ 2nd arg = min BLOCKS/CU (confirmed R11/R12: (512,4)->64 VGPR,
// (512,8)->32/16 VGPR). LDS 37.4KB caps at 4 blocks/CU; ask for exactly that ->
// VGPR cap 64 (was 16 in R6!) so staging + Horner can actually pipeline.
__global__ __launch_bounds__(512, 4) void kan_main(const float* __restrict__ x,
                                                   const float* __restrict__ wn,
                                                   const float* __restrict__ wd,
                                                   float* __restrict__ out) {
    __shared__ float xt[NIN * XSTR];    // 35072 B: xt[c][pos], pos = t*34+col
    __shared__ float red[512];

    // bijective XCD-chunked swizzle: 1024 blocks, 128 per XCD -> 8 f's per XCD L2
    int bid  = blockIdx.x;
    int wgid = (bid & 7) * 128 + (bid >> 3);
    int f    = wgid >> 4;
    int band = wgid & 15;
    int i0   = band * 2;

    int tid = threadIdx.x;

    // ---- stage x tile: 8704 floats = 17 * 512; global reads lane=c coalesced;
    // ---- ds_write addr = c*137 + pos -> bank (9c+pos)%32 -> 2-way alias (free) ----
#pragma unroll
    for (int k = 0; k < 17; ++k) {
        int idx = k * 512 + tid;
        int c   = idx & 63;
        int pos = idx >> 6;             // 0..135
        int t   = pos / 34;
        int col = pos % 34;
        int gi  = i0 - 1 + t;
        int gj  = col - 1;
        float v = 0.0f;
        if (gi >= 0 && gi < HH && gj >= 0 && gj < WW)
            v = x[(gi * WW + gj) * NIN + c];
        xt[c * XSTR + pos] = v;
    }
    __syncthreads();

    int lane = tid & 63;
    int wv   = __builtin_amdgcn_readfirstlane(tid >> 6);  // c-group 0..7 (SGPR)
    int r    = lane >> 5;               // row within band
    int j    = lane & 31;               // col

    float acc = 0.0f;

    const float* wnf = wn + (size_t)(f * NIN + wv * 8) * 54;  // [c][ab][6]
    const float* wdf = wd + (size_t)(f * NIN + wv * 8) * 36;  // [c][ab][4]

    for (int cc = 0; cc < 8; ++cc) {
        const float* wnc = wnf + cc * 54;   // uniform -> s_load
        const float* wdc = wdf + cc * 36;
        const float* xc  = &xt[(wv * 8 + cc) * XSTR + r * 34 + j];
#pragma unroll
        for (int a = 0; a < 3; ++a) {
#pragma unroll
            for (int b = 0; b < 3; ++b) {
                const int ab = a * 3 + b;
                float xv = xc[a * 34 + b];          // ds_read_b32, imm offset
                float pn = fmaf(wnc[ab * 6 + 5], xv, wnc[ab * 6 + 4]);
                pn = fmaf(pn, xv, wnc[ab * 6 + 3]);
                pn = fmaf(pn, xv, wnc[ab * 6 + 2]);
                pn = fmaf(pn, xv, wnc[ab * 6 + 1]);
                pn = fmaf(pn, xv, wnc[ab * 6 + 0]);
                float qn = fmaf(wdc[ab * 4 + 3], xv, wdc[ab * 4 + 2]);
                qn = fmaf(qn, xv, wdc[ab * 4 + 1]);
                qn = fmaf(qn, xv, wdc[ab * 4 + 0]);
                float den = 1.0f + fabsf(xv * qn);
                acc = fmaf(pn, __builtin_amdgcn_rcpf(den), acc);
            }
        }
    }

    // ---- reduce the 8 c-group partials per pixel; write once, coalesced ----
    red[tid] = acc;
    __syncthreads();
    if (tid < 64) {
        float s = red[tid]       + red[tid + 64]  + red[tid + 128] + red[tid + 192]
                + red[tid + 256] + red[tid + 320] + red[tid + 384] + red[tid + 448];
        int rr = tid >> 5;
        int jj = tid & 31;
        out[f * (HH * WW) + (i0 + rr) * WW + jj] = s;
    }
}

extern "C" void kernel_launch(void* const* d_in, const int* in_sizes, int n_in,
                              void* d_out, int out_size, void* d_ws, size_t ws_size,
                              hipStream_t stream) {
    const float* x  = (const float*)d_in[0];
    const float* wn = (const float*)d_in[1];
    const float* wd = (const float*)d_in[2];
    float* out = (float*)d_out;
    (void)d_ws; (void)ws_size; (void)in_sizes; (void)n_in; (void)out_size;

    kan_main<<<1024, 512, 0, stream>>>(x, wn, wd, out);
}